// Round 2
// baseline (185.030 us; speedup 1.0000x reference)
//
#include <hip/hip_runtime.h>
#include <cstdint>
#include <cstddef>

// ---------------------------------------------------------------------------
// Style2ResidualBlock1DSrc: modulated conv1d (StyleGAN2-style) on MI355X.
// R5: gemm rebuilt as 3-phase (per-tap) counted-vmcnt pipeline (T3+T4+T5):
//  - BM=128 BN=512 BK=32, 512 thr (8 waves 2Mx4N), grid 256 = 1 block/CU.
//  - LDS double-buffered: lA[2][3*128*32] + lB[2][514*32] = 112.25 KB.
//  - per K-step per wave: 3 A-stage + 5 B-stage gload_lds (uniform count),
//    gates vmcnt(6)/(7)/(2) placed BEFORE the phase barrier (template order:
//    own-wave gate -> barrier -> everyone's data published). Never vmcnt(0)
//    in the main loop; last K-step peeled with vmcnt(1)/(0) drain.
//  - setprio(1) around each 32-MFMA cluster (T5; phases create role-split).
//  - demod preloaded into regs before staging (FIFO-safe vs counted gates).
// Factorized weights kept from R4: A = bf16 Wb[3][512][512] (L2-resident),
// s folded into xT, demod applied in epilogue.
// ---------------------------------------------------------------------------

#define LIN_SCALE  0.0625f           // 1/sqrt(256)
#define CONV_SCALE 0.014731391f      // 1/sqrt(512*9)

#define B_   16
#define CIN  512
#define COUT 512
#define T_   2048
#define TP   2050                    // T + 2 pad rows

typedef __bf16 bf16x8 __attribute__((ext_vector_type(8)));
typedef float  f32x4  __attribute__((ext_vector_type(4)));
typedef unsigned short u16x8 __attribute__((ext_vector_type(8)));
typedef unsigned short u16x2 __attribute__((ext_vector_type(2)));

#define AS1 __attribute__((address_space(1)))
#define AS3 __attribute__((address_space(3)))

__device__ inline unsigned short f2bf(float f) {
  __bf16 h = (__bf16)f;              // RNE fptrunc
  return __builtin_bit_cast(unsigned short, h);
}

// ---------------- 1. style linear: s[b][i] ----------------
__global__ __launch_bounds__(256) void style_kernel(const float* __restrict__ c_src,
                                                    const float* __restrict__ c_trg,
                                                    const float* __restrict__ sw,
                                                    const float* __restrict__ sb,
                                                    float* __restrict__ s) {
  __shared__ float c[256];
  const int b = blockIdx.y;
  const int tid = threadIdx.x;
  c[tid] = (tid < 128) ? c_src[b * 128 + tid] : c_trg[b * 128 + tid - 128];
  __syncthreads();
  const int w = tid >> 6, lane = tid & 63;
  #pragma unroll
  for (int rr = 0; rr < 16; ++rr) {
    const int i = blockIdx.x * 64 + w * 16 + rr;
    const float* row = sw + (size_t)i * 256;
    float acc = row[lane] * c[lane] + row[lane + 64] * c[lane + 64]
              + row[lane + 128] * c[lane + 128] + row[lane + 192] * c[lane + 192];
    #pragma unroll
    for (int off = 32; off; off >>= 1) acc += __shfl_down(acc, off, 64);
    if (lane == 0) s[b * 512 + i] = acc * LIN_SCALE + sb[i];
  }
}

// ---------------- 2. demod[b][o] + base bf16 weight Wb[tap][o][i] ----------------
__global__ __launch_bounds__(256) void demod_kernel(const float* __restrict__ weight,
                                                    const float* __restrict__ s,
                                                    float* __restrict__ demod,
                                                    unsigned short* __restrict__ Wb) {
  const int o = blockIdx.x;
  const int tid = threadIdx.x;
  __shared__ float wsh[1536];        // weight[o][:][:]
  __shared__ float svs[16 * 512];    // all style vectors (32 KB)
  __shared__ float partial[16][4];

  #pragma unroll
  for (int j = tid; j < 384; j += 256)
    ((float4*)wsh)[j] = ((const float4*)(weight + (size_t)o * 1536))[j];
  #pragma unroll
  for (int j = tid; j < 2048; j += 256)
    ((float4*)svs)[j] = ((const float4*)s)[j];
  __syncthreads();

  float wr[6];
  #pragma unroll
  for (int q = 0; q < 6; ++q) wr[q] = wsh[tid * 6 + q] * CONV_SCALE;

  // batch-independent bf16 base weight: Wb[k][o][i], i = 2*tid, 2*tid+1
  #pragma unroll
  for (int k = 0; k < 3; ++k) {
    u16x2 v;
    v.x = f2bf(wr[k]);
    v.y = f2bf(wr[3 + k]);
    *(u16x2*)&Wb[((size_t)(k * 512 + o)) * 512 + 2 * tid] = v;
  }

  const int lane = tid & 63, w = tid >> 6;
  float ssb[16];
  #pragma unroll
  for (int b = 0; b < 16; ++b) {
    const float s0 = svs[b * 512 + 2 * tid];
    const float s1 = svs[b * 512 + 2 * tid + 1];
    float ss = 0.f;
    #pragma unroll
    for (int q = 0; q < 3; ++q) { float v = wr[q] * s0; ss += v * v; }
    #pragma unroll
    for (int q = 3; q < 6; ++q) { float v = wr[q] * s1; ss += v * v; }
    ssb[b] = ss;
  }
  #pragma unroll
  for (int b = 0; b < 16; ++b) {
    float ss = ssb[b];
    #pragma unroll
    for (int off = 32; off; off >>= 1) ss += __shfl_down(ss, off, 64);
    if (lane == 0) partial[b][w] = ss;
  }
  __syncthreads();
  if (tid < 16)
    demod[(size_t)tid * 512 + o] =
        rsqrtf(partial[tid][0] + partial[tid][1] + partial[tid][2] + partial[tid][3] + 1e-8f);
}

// ---------------- 3. transpose + pad + s-modulate + bf16 ----------------
__global__ __launch_bounds__(256) void transpose_kernel(const float* __restrict__ x,
                                                        const float* __restrict__ s,
                                                        unsigned short* __restrict__ xT) {
  __shared__ float tile[64][65];
  __shared__ float ss[64];
  const int b = blockIdx.z, i0 = blockIdx.y * 64, t0 = blockIdx.x * 64;
  const int tid = threadIdx.x;

  if (tid < 64) ss[tid] = s[(size_t)b * 512 + i0 + tid];

  const int lr = tid >> 4;            // 0..15
  const int lc = (tid & 15) * 4;      // float4
  const float* xb = x + ((size_t)b * CIN + i0) * T_ + t0;
  #pragma unroll
  for (int p = 0; p < 4; ++p) {
    const int r = p * 16 + lr;
    const float4 v = *(const float4*)(xb + (size_t)r * T_ + lc);
    tile[r][lc + 0] = v.x; tile[r][lc + 1] = v.y;
    tile[r][lc + 2] = v.z; tile[r][lc + 3] = v.w;
  }
  // fused zero-pad of rows 0 and 2049 (no barrier dependency)
  if (blockIdx.x == 0 && tid < 8)
    *(u16x8*)&xT[(size_t)b * TP * CIN + i0 + tid * 8] = (u16x8){0,0,0,0,0,0,0,0};
  if (blockIdx.x == gridDim.x - 1 && tid < 8)
    *(u16x8*)&xT[((size_t)b * TP + TP - 1) * CIN + i0 + tid * 8] = (u16x8){0,0,0,0,0,0,0,0};
  __syncthreads();

  const int st = tid >> 3;            // 0..31
  const int si = (tid & 7) * 8;       // 16B
  float sv[8];
  #pragma unroll
  for (int q = 0; q < 8; ++q) sv[q] = ss[si + q];
  unsigned short* xTb = xT + ((size_t)b * TP + 1 + t0) * CIN + i0;
  #pragma unroll
  for (int p = 0; p < 2; ++p) {
    const int t = p * 32 + st;
    u16x8 v;
    #pragma unroll
    for (int q = 0; q < 8; ++q) v[q] = f2bf(tile[si + q][t] * sv[q]);
    *(u16x8*)&xTb[(size_t)t * CIN + si] = v;
  }
}

// ---------------- 4. main GEMM: 3-phase counted-vmcnt pipeline ----------------
// out[b][o0..+128][t0..+512] = demod[b][o] * sum_{tap,i} Wb[tap][o][i] * xT[b][t0+lt+tap][i]
// Per K-step (BK=32): phase tap p = { ds_read frags(p); stage-next subset;
//   vmcnt(gate); s_barrier; lgkmcnt(0); 32 MFMA (setprio 1); s_barrier }.
// Stage schedule per K-step/wave: ph0: B x5, ph1: A0,A1, ph2: A2 (8 total).
// Gates: ph0 vmcnt(6) [A1 cur landed], ph1 vmcnt(7) [A2 cur], ph2 vmcnt(2)
// [B+A0 next landed]. FIFO-verified; peel kk=15 with vmcnt(1)/(0).
#define BM 128
#define BN 512

#define VMCNT(n) asm volatile("s_waitcnt vmcnt(" #n ")" ::: "memory")
#define LGKM0    asm volatile("s_waitcnt lgkmcnt(0)" ::: "memory")
#define BAR()    __builtin_amdgcn_s_barrier()
#define SB()     __builtin_amdgcn_sched_barrier(0)

#define STAGE_B(buf, i0g)                                                     \
  { _Pragma("unroll")                                                         \
    for (int q = 0; q < 4; ++q) {                                             \
      const int ci  = q * 512 + tid;                                          \
      const int row = ci >> 2;                                                \
      const int gc  = ((ci & 3) ^ ((row >> 1) & 3)) * 8;                      \
      __builtin_amdgcn_global_load_lds(                                       \
          (const AS1 void*)(gX + (size_t)row * CIN + (i0g) + gc),             \
          (AS3 void*)(&lB[buf][ci * 8]), 16, 0, 0);                           \
    }                                                                         \
    if (lane == 0) {                                                          \
      const int ci  = 2048 + wid;                                             \
      const int row = 512 + (wid >> 2);                                       \
      const int gc  = ((ci & 3) ^ ((row >> 1) & 3)) * 8;                      \
      __builtin_amdgcn_global_load_lds(                                       \
          (const AS1 void*)(gX + (size_t)row * CIN + (i0g) + gc),             \
          (AS3 void*)(&lB[buf][ci * 8]), 16, 0, 0);                           \
    } }

#define STAGE_A(buf, i0g, q)                                                  \
  { const int ci  = (q) * 512 + tid;                                          \
    const int ar  = tid >> 2;                                                 \
    const int gc  = ((ci & 3) ^ ((ar >> 1) & 3)) * 8;                         \
    __builtin_amdgcn_global_load_lds(                                         \
        (const AS1 void*)(gW + (size_t)(q) * 262144 + (size_t)ar * 512 + (i0g) + gc), \
        (AS3 void*)(&lA[buf][ci * 8]), 16, 0, 0);                             \
  }

#define FRAGS(tap)                                                            \
  bf16x8 af[4]; bf16x8 bfr[8];                                                \
  { const unsigned short* La = &lA[cur][0];                                   \
    const unsigned short* Lb = &lB[cur][0];                                   \
    _Pragma("unroll")                                                         \
    for (int mi = 0; mi < 4; ++mi) {                                          \
      const int ra = wm + mi * 16 + rl;                                       \
      af[mi] = *(const bf16x8*)&La[(((tap) * 128 + ra) * 4 + (kc ^ ((ra >> 1) & 3))) * 8]; \
    }                                                                         \
    _Pragma("unroll")                                                         \
    for (int ni = 0; ni < 8; ++ni) {                                          \
      const int rb = wn + ni * 16 + rl + (tap);                               \
      bfr[ni] = *(const bf16x8*)&Lb[(rb * 4 + (kc ^ ((rb >> 1) & 3))) * 8];   \
    } }

#define MFMAS()                                                               \
  __builtin_amdgcn_s_setprio(1);                                              \
  _Pragma("unroll")                                                           \
  for (int mi = 0; mi < 4; ++mi)                                              \
    _Pragma("unroll")                                                         \
    for (int ni = 0; ni < 8; ++ni)                                            \
      acc[mi][ni] = __builtin_amdgcn_mfma_f32_16x16x32_bf16(af[mi], bfr[ni], acc[mi][ni], 0, 0, 0); \
  __builtin_amdgcn_s_setprio(0);

__global__ __launch_bounds__(512, 2) void gemm_kernel(const unsigned short* __restrict__ Wb,
                                                      const unsigned short* __restrict__ xT,
                                                      const float* __restrict__ demod,
                                                      float* __restrict__ out) {
  __shared__ unsigned short lA[2][1536 * 8];   // [buf][(tap*128+ar)*4+c][8]  2x24576 B
  __shared__ unsigned short lB[2][2056 * 8];   // [buf][row*4+c][8] rows 0..513 2x32896 B

  // XCD b-grouping: 256 blocks; id==xcd (mod 8); 2 batches per XCD.
  const int id  = blockIdx.x;
  const int xcd = id & 7;
  const int j   = id >> 3;                 // 0..31
  const int b   = xcd + 8 * (j >> 4);      // 0..15
  const int r   = j & 15;
  const int o0  = (r >> 2) * BM;           // 4 o-blocks
  const int t0  = (r & 3) * BN;            // 4 t-blocks

  const int tid  = threadIdx.x;
  const int lane = tid & 63;
  const int wid  = tid >> 6;               // 0..7
  const int wm   = (wid & 1) * 64;         // 2 M-waves
  const int wn   = (wid >> 1) * 128;       // 4 N-waves
  const int rl   = lane & 15;
  const int kc   = lane >> 4;              // chunk 0..3 within 32-wide row

  const unsigned short* gW = Wb + (size_t)o0 * 512;            // batch-independent
  const unsigned short* gX = xT + ((size_t)b * TP + t0) * CIN;

  // demod preload (before staging; completes long before first gate —
  // gate arithmetic verified safe for any compiler placement of these loads)
  float dmv[16];
  {
    const float* dmp = demod + (size_t)b * 512 + o0 + wm + (lane >> 4) * 4;
    #pragma unroll
    for (int mi = 0; mi < 4; ++mi)
      #pragma unroll
      for (int rr = 0; rr < 4; ++rr) dmv[mi * 4 + rr] = dmp[mi * 16 + rr];
  }

  f32x4 acc[4][8];
  #pragma unroll
  for (int i = 0; i < 4; ++i)
    #pragma unroll
    for (int jj = 0; jj < 8; ++jj) acc[i][jj] = (f32x4){0.f, 0.f, 0.f, 0.f};

  // prologue: stage K-step 0 into buf 0; gate B+A0 landed (leaves A1,A2)
  STAGE_B(0, 0);
  STAGE_A(0, 0, 0);
  STAGE_A(0, 0, 1);
  STAGE_A(0, 0, 2);
  VMCNT(2); BAR(); SB();

  for (int kk = 0; kk < 15; ++kk) {
    const int cur = kk & 1;
    const int nxt = cur ^ 1;
    const int i0n = (kk + 1) * 32;
    { // phase 0: tap 0; stage B(next); gate A1(cur)
      FRAGS(0);
      STAGE_B(nxt, i0n);
      VMCNT(6); BAR(); SB(); LGKM0; SB();
      MFMAS(); BAR(); SB();
    }
    { // phase 1: tap 1; stage A0,A1(next); gate A2(cur)
      FRAGS(1);
      STAGE_A(nxt, i0n, 0);
      STAGE_A(nxt, i0n, 1);
      VMCNT(7); BAR(); SB(); LGKM0; SB();
      MFMAS(); BAR(); SB();
    }
    { // phase 2: tap 2; stage A2(next); gate B+A0(next) (leaves A1,A2 next)
      FRAGS(2);
      STAGE_A(nxt, i0n, 2);
      VMCNT(2); BAR(); SB(); LGKM0; SB();
      MFMAS(); BAR(); SB();
    }
  }
  { // kk = 15 peeled (no staging): gates drain 1 -> 0
    const int cur = 1;
    { FRAGS(0); VMCNT(1); BAR(); SB(); LGKM0; SB(); MFMAS(); BAR(); SB(); }
    { FRAGS(1); VMCNT(0); BAR(); SB(); LGKM0; SB(); MFMAS(); BAR(); SB(); }
    { FRAGS(2); LGKM0; SB(); MFMAS(); }
  }

  // epilogue: D row = (lane>>4)*4 + reg, col = lane&15 (m89 mapping); x demod
  float* ob = out + ((size_t)b * COUT + o0 + wm) * T_ + t0 + wn;
  const int rrow = (lane >> 4) * 4;
  const int ccol = lane & 15;
  #pragma unroll
  for (int mi = 0; mi < 4; ++mi)
    #pragma unroll
    for (int ni = 0; ni < 8; ++ni)
      #pragma unroll
      for (int rr = 0; rr < 4; ++rr)
        ob[(size_t)(mi * 16 + rrow + rr) * T_ + ni * 16 + ccol] = acc[mi][ni][rr] * dmv[mi * 4 + rr];
}

// ---------------------------------------------------------------------------
extern "C" void kernel_launch(void* const* d_in, const int* in_sizes, int n_in,
                              void* d_out, int out_size, void* d_ws, size_t ws_size,
                              hipStream_t stream) {
  const float* x       = (const float*)d_in[0];   // [16,512,2048]
  const float* c_src   = (const float*)d_in[1];   // [16,128]
  const float* c_trg   = (const float*)d_in[2];   // [16,128]
  const float* style_w = (const float*)d_in[3];   // [512,256]
  const float* style_b = (const float*)d_in[4];   // [512]
  const float* weight  = (const float*)d_in[5];   // [1,512,512,3]
  float* out = (float*)d_out;

  // workspace: s fp32 [16][512] @0; demod fp32 [16][512] @32768;
  //            Wb bf16 [3][512][512] @65536; xT bf16 [16][2050][512] @1638400
  char* ws = (char*)d_ws;
  float* s_buf          = (float*)ws;
  float* demod_buf      = (float*)(ws + 32768);
  unsigned short* Wb    = (unsigned short*)(ws + 65536);
  unsigned short* xTbuf = (unsigned short*)(ws + 65536 + 1572864);

  style_kernel<<<dim3(8, 16), 256, 0, stream>>>(c_src, c_trg, style_w, style_b, s_buf);
  demod_kernel<<<dim3(COUT), 256, 0, stream>>>(weight, s_buf, demod_buf, Wb);
  transpose_kernel<<<dim3(T_ / 64, CIN / 64, B_), 256, 0, stream>>>(x, s_buf, xTbuf);
  gemm_kernel<<<dim3(256), 512, 0, stream>>>(Wb, xTbuf, demod_buf, out);
}